// Round 1
// baseline (484.878 us; speedup 1.0000x reference)
//
#include <hip/hip_runtime.h>
#include <math.h>

#define B_    32
#define NPER_ 96
#define M_    3072
#define H_    8
#define CH_   16
#define PQK_  8
#define PV_   12
#define CS_   256
#define CZ_   128
#define E_    294912

// ---------------------------------------------------------------------------
// Generic tiled f32 GEMM: C[M,N] = A[M,K] @ W[K,N] + bias[N]
// 64x64 tile, 256 threads, 4x4 micro-tile per thread. M assumed multiple of 64.
// ---------------------------------------------------------------------------
template <bool ALIGN_A>
__global__ __launch_bounds__(256) void gemm64(const float* __restrict__ A,
                                              const float* __restrict__ W,
                                              const float* __restrict__ bias,
                                              float* __restrict__ C,
                                              int N, int K) {
  __shared__ float As[16][68];  // [k][m], padded stride 68 (16B-aligned rows, conflict-free)
  __shared__ float Bs[16][64];  // [k][n]
  const int tid = threadIdx.x;
  const int tx = tid & 15, ty = tid >> 4;
  const int row0 = blockIdx.y * 64, col0 = blockIdx.x * 64;
  float acc[4][4] = {};

  for (int k0 = 0; k0 < K; k0 += 16) {
    {  // A tile: 64 rows x 16 k
      const int m = tid >> 2, k4 = (tid & 3) * 4;
      const int gk = k0 + k4;
      float a0 = 0.f, a1 = 0.f, a2 = 0.f, a3 = 0.f;
      if (ALIGN_A) {  // K % 16 == 0
        const float4 av = *reinterpret_cast<const float4*>(A + (size_t)(row0 + m) * K + gk);
        a0 = av.x; a1 = av.y; a2 = av.z; a3 = av.w;
      } else {
        const float* ap = A + (size_t)(row0 + m) * K;
        if (gk + 0 < K) a0 = ap[gk + 0];
        if (gk + 1 < K) a1 = ap[gk + 1];
        if (gk + 2 < K) a2 = ap[gk + 2];
        if (gk + 3 < K) a3 = ap[gk + 3];
      }
      As[k4 + 0][m] = a0; As[k4 + 1][m] = a1; As[k4 + 2][m] = a2; As[k4 + 3][m] = a3;
    }
    {  // B tile: 16 k x 64 n
      const int kk = tid >> 4, n4 = (tid & 15) * 4;
      const int gk = k0 + kk, gn = col0 + n4;
      float4 bv; bv.x = 0.f; bv.y = 0.f; bv.z = 0.f; bv.w = 0.f;
      if (gk < K) {
        if (gn + 3 < N) {
          bv = *reinterpret_cast<const float4*>(W + (size_t)gk * N + gn);
        } else {
          const float* wp = W + (size_t)gk * N;
          if (gn + 0 < N) bv.x = wp[gn + 0];
          if (gn + 1 < N) bv.y = wp[gn + 1];
          if (gn + 2 < N) bv.z = wp[gn + 2];
          if (gn + 3 < N) bv.w = wp[gn + 3];
        }
      }
      *reinterpret_cast<float4*>(&Bs[kk][n4]) = bv;
    }
    __syncthreads();
#pragma unroll
    for (int kk = 0; kk < 16; ++kk) {
      const float4 a_ = *reinterpret_cast<const float4*>(&As[kk][ty * 4]);
      const float4 b_ = *reinterpret_cast<const float4*>(&Bs[kk][tx * 4]);
      acc[0][0] += a_.x * b_.x; acc[0][1] += a_.x * b_.y; acc[0][2] += a_.x * b_.z; acc[0][3] += a_.x * b_.w;
      acc[1][0] += a_.y * b_.x; acc[1][1] += a_.y * b_.y; acc[1][2] += a_.y * b_.z; acc[1][3] += a_.y * b_.w;
      acc[2][0] += a_.z * b_.x; acc[2][1] += a_.z * b_.y; acc[2][2] += a_.z * b_.z; acc[2][3] += a_.z * b_.w;
      acc[3][0] += a_.w * b_.x; acc[3][1] += a_.w * b_.y; acc[3][2] += a_.w * b_.z; acc[3][3] += a_.w * b_.w;
    }
    __syncthreads();
  }
#pragma unroll
  for (int i2 = 0; i2 < 4; ++i2) {
    const int gr = row0 + ty * 4 + i2;
#pragma unroll
    for (int j2 = 0; j2 < 4; ++j2) {
      const int gn = col0 + tx * 4 + j2;
      if (gn < N) C[(size_t)gr * N + gn] = acc[i2][j2] + bias[gn];
    }
  }
}

// ---------------------------------------------------------------------------
// Rotate raw point projections into global frame; also seed o_feats L columns.
// praw_q  [M][192]: idx = d*64  + h*8  + p   (d=0..2, H*PQK=64)
// praw_kv [M][480]: idx = d*160 + h*20 + p   (H*(PQK+PV)=160)
// outputs: qpts/kpts [M*8*8*3], vpts [M*8*12*3] as [m][h][p][d] contiguous
// ---------------------------------------------------------------------------
__global__ __launch_bounds__(256) void rotate_pts(const float* __restrict__ praw_q,
                                                  const float* __restrict__ praw_kv,
                                                  const float* __restrict__ rot,
                                                  const float* __restrict__ trans,
                                                  const float* __restrict__ L,
                                                  float* __restrict__ qpts,
                                                  float* __restrict__ kpts,
                                                  float* __restrict__ vpts,
                                                  float* __restrict__ ofeat) {
  const int m = blockIdx.x;
  const int t = threadIdx.x;
  float R[9], T[3];
#pragma unroll
  for (int a = 0; a < 9; ++a) R[a] = rot[m * 9 + a];  // uniform -> s_load
#pragma unroll
  for (int a = 0; a < 3; ++a) T[a] = trans[m * 3 + a];

  if (t < 64) {  // q_pts: t = h*8+p
    const float x = praw_q[(size_t)m * 192 + t];
    const float y = praw_q[(size_t)m * 192 + 64 + t];
    const float z = praw_q[(size_t)m * 192 + 128 + t];
    const int h = t >> 3, p = t & 7;
    float* dst = qpts + ((size_t)(m * 8 + h) * 8 + p) * 3;
    dst[0] = R[0] * x + R[1] * y + R[2] * z + T[0];
    dst[1] = R[3] * x + R[4] * y + R[5] * z + T[1];
    dst[2] = R[6] * x + R[7] * y + R[8] * z + T[2];
  } else if (t < 224) {  // kv_pts: idx = h*20+p
    const int idx = t - 64;
    const float x = praw_kv[(size_t)m * 480 + idx];
    const float y = praw_kv[(size_t)m * 480 + 160 + idx];
    const float z = praw_kv[(size_t)m * 480 + 320 + idx];
    const int h = idx / 20, p = idx % 20;
    const float o0 = R[0] * x + R[1] * y + R[2] * z + T[0];
    const float o1 = R[3] * x + R[4] * y + R[5] * z + T[1];
    const float o2 = R[6] * x + R[7] * y + R[8] * z + T[2];
    float* dst = (p < 8) ? (kpts + ((size_t)(m * 8 + h) * 8 + p) * 3)
                         : (vpts + ((size_t)(m * 8 + h) * 12 + (p - 8)) * 3);
    dst[0] = o0; dst[1] = o1; dst[2] = o2;
  } else if (t < 230) {  // o_feats[:, 416..421] = L[batch]
    ofeat[(size_t)m * 422 + 416 + (t - 224)] = L[(m / NPER_) * 6 + (t - 224)];
  }
}

// ---------------------------------------------------------------------------
// bT[h][e] = z[e] . Wb[:,h] + bb[h]   (head-major transposed for attn reads)
// One wave per row: lane l covers z cols {2l,2l+1}; butterfly reduction that
// specializes lanes to heads (3 select levels + 3 plain levels).
// ---------------------------------------------------------------------------
__global__ __launch_bounds__(256) void bpair_kernel(const float* __restrict__ z,
                                                    const float* __restrict__ Wb,
                                                    const float* __restrict__ bb,
                                                    float* __restrict__ bT) {
  const int l = threadIdx.x & 63;
  const int wave = blockIdx.x * 4 + (threadIdx.x >> 6);
  const int nw = gridDim.x * 4;
  const float4* W4 = reinterpret_cast<const float4*>(Wb);
  const float4 w0 = W4[l * 4 + 0];  // Wb[2l][0..3]
  const float4 w1 = W4[l * 4 + 1];  // Wb[2l][4..7]
  const float4 w2 = W4[l * 4 + 2];  // Wb[2l+1][0..3]
  const float4 w3 = W4[l * 4 + 3];  // Wb[2l+1][4..7]
  const int b0 = l & 1, b1 = (l >> 1) & 1, b2 = (l >> 2) & 1;
  const int myh = (b0 << 2) | (b1 << 1) | b2;
  const float mybb = bb[myh];
  const float2* z2 = reinterpret_cast<const float2*>(z);

  for (int row = wave; row < E_; row += nw) {
    const float2 zv = z2[(size_t)row * 64 + l];
    float a0 = zv.x * w0.x + zv.y * w2.x;
    float a1 = zv.x * w0.y + zv.y * w2.y;
    float a2 = zv.x * w0.z + zv.y * w2.z;
    float a3 = zv.x * w0.w + zv.y * w2.w;
    float a4 = zv.x * w1.x + zv.y * w3.x;
    float a5 = zv.x * w1.y + zv.y * w3.y;
    float a6 = zv.x * w1.z + zv.y * w3.z;
    float a7 = zv.x * w1.w + zv.y * w3.w;
    // level 1 (xor 1): keep 4 heads selected by b0
    float s40 = (b0 ? a4 : a0) + __shfl_xor(b0 ? a0 : a4, 1);
    float s41 = (b0 ? a5 : a1) + __shfl_xor(b0 ? a1 : a5, 1);
    float s42 = (b0 ? a6 : a2) + __shfl_xor(b0 ? a2 : a6, 1);
    float s43 = (b0 ? a7 : a3) + __shfl_xor(b0 ? a3 : a7, 1);
    // level 2 (xor 2): keep 2 by b1
    float s20 = (b1 ? s42 : s40) + __shfl_xor(b1 ? s40 : s42, 2);
    float s21 = (b1 ? s43 : s41) + __shfl_xor(b1 ? s41 : s43, 2);
    // level 3 (xor 4): keep 1 by b2
    float s1 = (b2 ? s21 : s20) + __shfl_xor(b2 ? s20 : s21, 4);
    // full adds across remaining lane groups
    s1 += __shfl_xor(s1, 8);
    s1 += __shfl_xor(s1, 16);
    s1 += __shfl_xor(s1, 32);
    if (l < 8) bT[(size_t)myh * E_ + row] = s1 + mybb;
  }
}

// ---------------------------------------------------------------------------
// Attention: one block per (batch, head). 384 threads = 96 query rows x 4.
// Lane group (j, qq): qq covers srcs i = 4s+qq (s=0..23). Softmax & output
// reduced over qq with __shfl_xor(1/2). Writes o_feats slices.
// ---------------------------------------------------------------------------
__global__ __launch_bounds__(384) void attn_kernel(const float* __restrict__ qbuf,
                                                   const float* __restrict__ kvbuf,
                                                   const float* __restrict__ qpts,
                                                   const float* __restrict__ kpts,
                                                   const float* __restrict__ vpts,
                                                   const float* __restrict__ bT,
                                                   const float* __restrict__ L,
                                                   const float* __restrict__ Wl,
                                                   const float* __restrict__ bl,
                                                   const float* __restrict__ hwts,
                                                   float* __restrict__ ofeat) {
  const int b = blockIdx.x >> 3, h = blockIdx.x & 7;
  __shared__ float4 k4[96 * 4];
  __shared__ float4 v4[96 * 4];
  __shared__ float4 kp4[96 * 6];
  __shared__ float4 vp4[96 * 9];
  const int tid = threadIdx.x;

  for (int t = tid; t < 96 * 4; t += 384) {
    const int i = t >> 2, c4 = t & 3;
    const float4* src = reinterpret_cast<const float4*>(kvbuf + ((size_t)(b * 96 + i) * 8 + h) * 32);
    k4[t] = src[c4];
    v4[t] = src[4 + c4];
  }
  for (int t = tid; t < 96 * 6; t += 384) {
    const int i = t / 6, c4 = t - i * 6;
    kp4[t] = reinterpret_cast<const float4*>(kpts + ((size_t)(b * 96 + i) * 8 + h) * 24)[c4];
  }
  for (int t = tid; t < 96 * 9; t += 384) {
    const int i = t / 9, c4 = t - i * 9;
    vp4[t] = reinterpret_cast<const float4*>(vpts + ((size_t)(b * 96 + i) * 8 + h) * 36)[c4];
  }
  __syncthreads();

  const int j = tid >> 2, qq = tid & 3;
  const int mj = b * 96 + j;

  // uniform per-(b,h) scalars
  float lb = bl[h];
#pragma unroll
  for (int d = 0; d < 6; ++d) lb += L[b * 6 + d] * Wl[d * 8 + h];
  const float c_l = 0.5f * lb;
  const float sp = logf(1.0f + __expf(hwts[h]));       // softplus
  const float c_pt = 0.5f * sp * (1.0f / 12.0f);       // 0.5*hw,  hw = sp*sqrt(1/144)

  const float4* q4 = reinterpret_cast<const float4*>(qbuf + (size_t)mj * 128 + h * 16);
  const float4 qa = q4[0], qb = q4[1], qc = q4[2], qd = q4[3];
  float qp[24];
  {
    const float4* qp4 = reinterpret_cast<const float4*>(qpts + ((size_t)mj * 8 + h) * 24);
#pragma unroll
    for (int c4 = 0; c4 < 6; ++c4) {
      const float4 v_ = qp4[c4];
      qp[c4 * 4 + 0] = v_.x; qp[c4 * 4 + 1] = v_.y; qp[c4 * 4 + 2] = v_.z; qp[c4 * 4 + 3] = v_.w;
    }
  }
  const float* bTrow = bT + (size_t)h * E_ + (size_t)b * (96 * 96) + j;

  float lg[24];
  float mx = -3.0e38f;
#pragma unroll
  for (int s = 0; s < 24; ++s) {
    const int i = s * 4 + qq;
    const float4 ka = k4[i * 4 + 0], kb = k4[i * 4 + 1], kc = k4[i * 4 + 2], kd = k4[i * 4 + 3];
    float dot = qa.x * ka.x + qa.y * ka.y + qa.z * ka.z + qa.w * ka.w
              + qb.x * kb.x + qb.y * kb.y + qb.z * kb.z + qb.w * kb.w
              + qc.x * kc.x + qc.y * kc.y + qc.z * kc.z + qc.w * kc.w
              + qd.x * kd.x + qd.y * kd.y + qd.z * kd.z + qd.w * kd.w;
    float pd = 0.f;
#pragma unroll
    for (int c4 = 0; c4 < 6; ++c4) {
      const float4 kp = kp4[i * 6 + c4];
      const float d0 = qp[c4 * 4 + 0] - kp.x;
      const float d1 = qp[c4 * 4 + 1] - kp.y;
      const float d2 = qp[c4 * 4 + 2] - kp.z;
      const float d3 = qp[c4 * 4 + 3] - kp.w;
      pd += d0 * d0 + d1 * d1 + d2 * d2 + d3 * d3;
    }
    const float lv = dot * 0.125f + 0.5f * bTrow[(size_t)i * 96] + c_l - c_pt * pd;
    lg[s] = lv;
    mx = fmaxf(mx, lv);
  }
  mx = fmaxf(mx, __shfl_xor(mx, 1));
  mx = fmaxf(mx, __shfl_xor(mx, 2));
  float sum = 0.f;
#pragma unroll
  for (int s = 0; s < 24; ++s) { lg[s] = __expf(lg[s] - mx); sum += lg[s]; }
  sum += __shfl_xor(sum, 1);
  sum += __shfl_xor(sum, 2);
  const float inv = 1.0f / sum;

  float acco[16] = {};
  float accp[36] = {};
#pragma unroll
  for (int s = 0; s < 24; ++s) {
    const int i = s * 4 + qq;
    const float w = lg[s];
#pragma unroll
    for (int c4 = 0; c4 < 4; ++c4) {
      const float4 vv = v4[i * 4 + c4];
      acco[c4 * 4 + 0] += w * vv.x; acco[c4 * 4 + 1] += w * vv.y;
      acco[c4 * 4 + 2] += w * vv.z; acco[c4 * 4 + 3] += w * vv.w;
    }
#pragma unroll
    for (int c4 = 0; c4 < 9; ++c4) {
      const float4 pv = vp4[i * 9 + c4];
      accp[c4 * 4 + 0] += w * pv.x; accp[c4 * 4 + 1] += w * pv.y;
      accp[c4 * 4 + 2] += w * pv.z; accp[c4 * 4 + 3] += w * pv.w;
    }
  }
#pragma unroll
  for (int u = 0; u < 16; ++u) { acco[u] += __shfl_xor(acco[u], 1); acco[u] += __shfl_xor(acco[u], 2); }
#pragma unroll
  for (int u = 0; u < 36; ++u) { accp[u] += __shfl_xor(accp[u], 1); accp[u] += __shfl_xor(accp[u], 2); }

  if (qq == 0) {
    float* orow = ofeat + (size_t)mj * 422;
#pragma unroll
    for (int c = 0; c < 16; ++c) orow[h * 16 + c] = acco[c] * inv;
#pragma unroll
    for (int d = 0; d < 3; ++d)
#pragma unroll
      for (int p = 0; p < 12; ++p)
        orow[128 + d * 96 + h * 12 + p] = accp[p * 3 + d] * inv;  // accp is [p][d]
  }
}

// ---------------------------------------------------------------------------
extern "C" void kernel_launch(void* const* d_in, const int* in_sizes, int n_in,
                              void* d_out, int out_size, void* d_ws, size_t ws_size,
                              hipStream_t stream) {
  const float* s     = (const float*)d_in[0];
  const float* z     = (const float*)d_in[1];
  const float* rot   = (const float*)d_in[2];
  const float* trans = (const float*)d_in[3];
  const float* L     = (const float*)d_in[4];
  const float* Wq    = (const float*)d_in[5];
  const float* bq    = (const float*)d_in[6];
  const float* Wkv   = (const float*)d_in[7];
  const float* bkv   = (const float*)d_in[8];
  const float* Wqp   = (const float*)d_in[9];
  const float* bqp   = (const float*)d_in[10];
  const float* Wkvp  = (const float*)d_in[11];
  const float* bkvp  = (const float*)d_in[12];
  const float* Wb    = (const float*)d_in[13];
  const float* bb    = (const float*)d_in[14];
  const float* Wl    = (const float*)d_in[15];
  const float* bl    = (const float*)d_in[16];
  const float* hwts  = (const float*)d_in[17];
  const float* Wout  = (const float*)d_in[18];
  const float* bout  = (const float*)d_in[19];
  float* out = (float*)d_out;
  float* ws  = (float*)d_ws;

  // workspace layout (floats); praw_* aliased into bT region (dead before bpair)
  float* q_buf   = ws;                  // [M,128]   393216
  float* kv_buf  = q_buf  + 393216;     // [M,256]   786432
  float* qpts    = kv_buf + 786432;     // [M,8,8,3] 589824
  float* kpts    = qpts   + 589824;     // 589824
  float* vpts    = kpts   + 589824;     // [M,8,12,3] 884736
  float* ofeat   = vpts   + 884736;     // [M,422]   1296384
  float* bT      = ofeat  + 1296384;    // [8,E]     2359296   (total 27.6 MB)
  float* praw_q  = bT;                  // [M,192]   589824  (alias)
  float* praw_kv = bT + 589824;         // [M,480]   1474560 (alias)

  gemm64<true ><<<dim3(2, 48), 256, 0, stream>>>(s, Wq,   bq,   q_buf,   128, 256);
  gemm64<true ><<<dim3(4, 48), 256, 0, stream>>>(s, Wkv,  bkv,  kv_buf,  256, 256);
  gemm64<true ><<<dim3(3, 48), 256, 0, stream>>>(s, Wqp,  bqp,  praw_q,  192, 256);
  gemm64<true ><<<dim3(8, 48), 256, 0, stream>>>(s, Wkvp, bkvp, praw_kv, 480, 256);
  rotate_pts<<<M_, 256, 0, stream>>>(praw_q, praw_kv, rot, trans, L, qpts, kpts, vpts, ofeat);
  bpair_kernel<<<2048, 256, 0, stream>>>(z, Wb, bb, bT);
  attn_kernel<<<256, 384, 0, stream>>>(q_buf, kv_buf, qpts, kpts, vpts, bT, L, Wl, bl, hwts, ofeat);
  gemm64<false><<<dim3(4, 48), 256, 0, stream>>>(ofeat, Wout, bout, out, 256, 422);
}

// Round 3
// 370.033 us; speedup vs baseline: 1.3104x; 1.3104x over previous
//
#include <hip/hip_runtime.h>
#include <math.h>

#define B_    32
#define NPER_ 96
#define M_    3072
#define H_    8
#define CH_   16
#define PQK_  8
#define PV_   12
#define CS_   256
#define CZ_   128
#define E_    294912
#define NCAT_ 1056

// ---------------------------------------------------------------------------
// Generic tiled f32 GEMM: C[M,N] = A[M,K] @ W[K,N] + bias[N]
// 64x64 tile, 256 threads, 4x4 micro-tile per thread. M assumed multiple of 64.
// ---------------------------------------------------------------------------
template <bool ALIGN_A>
__global__ __launch_bounds__(256) void gemm64(const float* __restrict__ A,
                                              const float* __restrict__ W,
                                              const float* __restrict__ bias,
                                              float* __restrict__ C,
                                              int N, int K) {
  __shared__ float As[16][68];
  __shared__ float Bs[16][64];
  const int tid = threadIdx.x;
  const int tx = tid & 15, ty = tid >> 4;
  const int row0 = blockIdx.y * 64, col0 = blockIdx.x * 64;
  float acc[4][4] = {};

  for (int k0 = 0; k0 < K; k0 += 16) {
    {
      const int m = tid >> 2, k4 = (tid & 3) * 4;
      const int gk = k0 + k4;
      float a0 = 0.f, a1 = 0.f, a2 = 0.f, a3 = 0.f;
      if (ALIGN_A) {
        const float4 av = *reinterpret_cast<const float4*>(A + (size_t)(row0 + m) * K + gk);
        a0 = av.x; a1 = av.y; a2 = av.z; a3 = av.w;
      } else {
        const float* ap = A + (size_t)(row0 + m) * K;
        if (gk + 0 < K) a0 = ap[gk + 0];
        if (gk + 1 < K) a1 = ap[gk + 1];
        if (gk + 2 < K) a2 = ap[gk + 2];
        if (gk + 3 < K) a3 = ap[gk + 3];
      }
      As[k4 + 0][m] = a0; As[k4 + 1][m] = a1; As[k4 + 2][m] = a2; As[k4 + 3][m] = a3;
    }
    {
      const int kk = tid >> 4, n4 = (tid & 15) * 4;
      const int gk = k0 + kk, gn = col0 + n4;
      float4 bv; bv.x = 0.f; bv.y = 0.f; bv.z = 0.f; bv.w = 0.f;
      if (gk < K) {
        if (gn + 3 < N) {
          bv = *reinterpret_cast<const float4*>(W + (size_t)gk * N + gn);
        } else {
          const float* wp = W + (size_t)gk * N;
          if (gn + 0 < N) bv.x = wp[gn + 0];
          if (gn + 1 < N) bv.y = wp[gn + 1];
          if (gn + 2 < N) bv.z = wp[gn + 2];
          if (gn + 3 < N) bv.w = wp[gn + 3];
        }
      }
      *reinterpret_cast<float4*>(&Bs[kk][n4]) = bv;
    }
    __syncthreads();
#pragma unroll
    for (int kk = 0; kk < 16; ++kk) {
      const float4 a_ = *reinterpret_cast<const float4*>(&As[kk][ty * 4]);
      const float4 b_ = *reinterpret_cast<const float4*>(&Bs[kk][tx * 4]);
      acc[0][0] += a_.x * b_.x; acc[0][1] += a_.x * b_.y; acc[0][2] += a_.x * b_.z; acc[0][3] += a_.x * b_.w;
      acc[1][0] += a_.y * b_.x; acc[1][1] += a_.y * b_.y; acc[1][2] += a_.y * b_.z; acc[1][3] += a_.y * b_.w;
      acc[2][0] += a_.z * b_.x; acc[2][1] += a_.z * b_.y; acc[2][2] += a_.z * b_.z; acc[2][3] += a_.z * b_.w;
      acc[3][0] += a_.w * b_.x; acc[3][1] += a_.w * b_.y; acc[3][2] += a_.w * b_.z; acc[3][3] += a_.w * b_.w;
    }
    __syncthreads();
  }
#pragma unroll
  for (int i2 = 0; i2 < 4; ++i2) {
    const int gr = row0 + ty * 4 + i2;
#pragma unroll
    for (int j2 = 0; j2 < 4; ++j2) {
      const int gn = col0 + tx * 4 + j2;
      if (gn < N) C[(size_t)gr * N + gn] = acc[i2][j2] + bias[gn];
    }
  }
}

// ---------------------------------------------------------------------------
// Pack the 4 projection weight matrices into Wcat[256][1056] (+ bcat[1056]).
// Column ranges: q [0,128) | kv [128,384) | qp [384,576) | kvp [576,1056)
// ---------------------------------------------------------------------------
__global__ __launch_bounds__(256) void pack_w(const float* __restrict__ Wq,
                                              const float* __restrict__ Wkv,
                                              const float* __restrict__ Wqp,
                                              const float* __restrict__ Wkvp,
                                              const float* __restrict__ bq,
                                              const float* __restrict__ bkv,
                                              const float* __restrict__ bqp,
                                              const float* __restrict__ bkvp,
                                              float* __restrict__ Wcat,
                                              float* __restrict__ bcat) {
  const int t = blockIdx.x * 256 + threadIdx.x;
  if (t < 256 * NCAT_) {
    const int k = t / NCAT_, n = t - k * NCAT_;
    float v;
    if (n < 128)      v = Wq [k * 128 + n];
    else if (n < 384) v = Wkv[k * 256 + n - 128];
    else if (n < 576) v = Wqp[k * 192 + n - 384];
    else              v = Wkvp[k * 480 + n - 576];
    Wcat[t] = v;
  }
  if (t < NCAT_) {
    float v;
    if (t < 128)      v = bq[t];
    else if (t < 384) v = bkv[t - 128];
    else if (t < 576) v = bqp[t - 384];
    else              v = bkvp[t - 576];
    bcat[t] = v;
  }
}

// ---------------------------------------------------------------------------
// Rotate raw point projections into global frame; also seed o_feats L columns.
// praw row layout [1056]: qp at 384 + d*64 + h*8 + p ; kvp at 576 + d*160 + h*20 + p
// ---------------------------------------------------------------------------
__global__ __launch_bounds__(256) void rotate_pts(const float* __restrict__ praw,
                                                  const float* __restrict__ rot,
                                                  const float* __restrict__ trans,
                                                  const float* __restrict__ L,
                                                  float* __restrict__ qpts,
                                                  float* __restrict__ kpts,
                                                  float* __restrict__ vpts,
                                                  float* __restrict__ ofeat) {
  const int m = blockIdx.x;
  const int t = threadIdx.x;
  float R[9], T[3];
#pragma unroll
  for (int a = 0; a < 9; ++a) R[a] = rot[m * 9 + a];
#pragma unroll
  for (int a = 0; a < 3; ++a) T[a] = trans[m * 3 + a];
  const float* prow = praw + (size_t)m * NCAT_;

  if (t < 64) {  // q_pts: t = h*8+p
    const float x = prow[384 + t];
    const float y = prow[384 + 64 + t];
    const float z = prow[384 + 128 + t];
    const int h = t >> 3, p = t & 7;
    float* dst = qpts + ((size_t)(m * 8 + h) * 8 + p) * 3;
    dst[0] = R[0] * x + R[1] * y + R[2] * z + T[0];
    dst[1] = R[3] * x + R[4] * y + R[5] * z + T[1];
    dst[2] = R[6] * x + R[7] * y + R[8] * z + T[2];
  } else if (t < 224) {  // kv_pts: idx = h*20+p
    const int idx = t - 64;
    const float x = prow[576 + idx];
    const float y = prow[576 + 160 + idx];
    const float z = prow[576 + 320 + idx];
    const int h = idx / 20, p = idx % 20;
    const float o0 = R[0] * x + R[1] * y + R[2] * z + T[0];
    const float o1 = R[3] * x + R[4] * y + R[5] * z + T[1];
    const float o2 = R[6] * x + R[7] * y + R[8] * z + T[2];
    float* dst = (p < 8) ? (kpts + ((size_t)(m * 8 + h) * 8 + p) * 3)
                         : (vpts + ((size_t)(m * 8 + h) * 12 + (p - 8)) * 3);
    dst[0] = o0; dst[1] = o1; dst[2] = o2;
  } else if (t < 230) {
    ofeat[(size_t)m * 422 + 416 + (t - 224)] = L[(m / NPER_) * 6 + (t - 224)];
  }
}

// ---------------------------------------------------------------------------
// bT2[h][b][j][i] = z[e] . Wb[:,h] + bb[h], where e = b*9216 + i*96 + j.
// Transposed-tile layout so attn stages one contiguous 36KB chunk per block.
// ---------------------------------------------------------------------------
__global__ __launch_bounds__(256) void bpair_kernel(const float* __restrict__ z,
                                                    const float* __restrict__ Wb,
                                                    const float* __restrict__ bb,
                                                    float* __restrict__ bT2) {
  const int l = threadIdx.x & 63;
  const int wave = blockIdx.x * 4 + (threadIdx.x >> 6);
  const int nw = gridDim.x * 4;
  const float4* W4 = reinterpret_cast<const float4*>(Wb);
  const float4 w0 = W4[l * 4 + 0];
  const float4 w1 = W4[l * 4 + 1];
  const float4 w2 = W4[l * 4 + 2];
  const float4 w3 = W4[l * 4 + 3];
  const int b0 = l & 1, b1 = (l >> 1) & 1, b2 = (l >> 2) & 1;
  const int myh = (b0 << 2) | (b1 << 1) | b2;
  const float mybb = bb[myh];
  const float2* z2 = reinterpret_cast<const float2*>(z);

  for (int row = wave; row < E_; row += nw) {
    const float2 zv = z2[(size_t)row * 64 + l];
    float a0 = zv.x * w0.x + zv.y * w2.x;
    float a1 = zv.x * w0.y + zv.y * w2.y;
    float a2 = zv.x * w0.z + zv.y * w2.z;
    float a3 = zv.x * w0.w + zv.y * w2.w;
    float a4 = zv.x * w1.x + zv.y * w3.x;
    float a5 = zv.x * w1.y + zv.y * w3.y;
    float a6 = zv.x * w1.z + zv.y * w3.z;
    float a7 = zv.x * w1.w + zv.y * w3.w;
    float s40 = (b0 ? a4 : a0) + __shfl_xor(b0 ? a0 : a4, 1);
    float s41 = (b0 ? a5 : a1) + __shfl_xor(b0 ? a1 : a5, 1);
    float s42 = (b0 ? a6 : a2) + __shfl_xor(b0 ? a2 : a6, 1);
    float s43 = (b0 ? a7 : a3) + __shfl_xor(b0 ? a3 : a7, 1);
    float s20 = (b1 ? s42 : s40) + __shfl_xor(b1 ? s40 : s42, 2);
    float s21 = (b1 ? s43 : s41) + __shfl_xor(b1 ? s41 : s43, 2);
    float s1 = (b2 ? s21 : s20) + __shfl_xor(b2 ? s20 : s21, 4);
    s1 += __shfl_xor(s1, 8);
    s1 += __shfl_xor(s1, 16);
    s1 += __shfl_xor(s1, 32);
    if (l < 8) {
      const int bb_ = row / 9216;
      const int el = row - bb_ * 9216;
      const int i = el / 96;
      const int jj = el - i * 96;
      bT2[(size_t)myh * E_ + (size_t)bb_ * 9216 + jj * 96 + i] = s1 + mybb;
    }
  }
}

// ---------------------------------------------------------------------------
// Attention: one block per (batch, head). 768 threads = 96 rows x 8 lanes.
// Lane (j,qq): qq covers srcs i = 8s+qq (s=0..11). Bias tile staged in LDS.
// k4/v4 padded to 5 float4/row (bank-conflict-free); lds_b stride 100.
// ---------------------------------------------------------------------------
__global__ __launch_bounds__(768, 3) void attn_kernel(const float* __restrict__ praw,
                                                      const float* __restrict__ qpts,
                                                      const float* __restrict__ kpts,
                                                      const float* __restrict__ vpts,
                                                      const float* __restrict__ bT2,
                                                      const float* __restrict__ L,
                                                      const float* __restrict__ Wl,
                                                      const float* __restrict__ bl,
                                                      const float* __restrict__ hwts,
                                                      float* __restrict__ ofeat) {
  const int b = blockIdx.x >> 3, h = blockIdx.x & 7;
  __shared__ float4 k4[96 * 5];
  __shared__ float4 v4[96 * 5];
  __shared__ float4 kp4[96 * 6];
  __shared__ float4 vp4[96 * 9];
  __shared__ float lds_b[96 * 100];
  const int tid = threadIdx.x;

  {  // k/v: 96 rows x 8 float4 = 768 elems, one per thread
    const int i = tid >> 3, c = tid & 7;
    const float4* src = reinterpret_cast<const float4*>(praw + (size_t)(b * 96 + i) * NCAT_ + 128 + h * 32);
    if (c < 4) k4[i * 5 + c] = src[c];
    else       v4[i * 5 + (c - 4)] = src[c];
  }
  for (int t = tid; t < 96 * 6; t += 768) {
    const int i = t / 6, c = t - i * 6;
    kp4[t] = reinterpret_cast<const float4*>(kpts + ((size_t)(b * 96 + i) * 8 + h) * 24)[c];
  }
  for (int t = tid; t < 96 * 9; t += 768) {
    const int i = t / 9, c = t - i * 9;
    vp4[t] = reinterpret_cast<const float4*>(vpts + ((size_t)(b * 96 + i) * 8 + h) * 36)[c];
  }
  {  // bias tile: 9216 floats contiguous -> lds_b[j*100 + i]
    const float4* g4 = reinterpret_cast<const float4*>(bT2 + (size_t)h * E_ + (size_t)b * 9216);
    for (int t = tid; t < 2304; t += 768) {
      const int jj = t / 24, c = t - jj * 24;
      reinterpret_cast<float4*>(lds_b + jj * 100)[c] = g4[t];
    }
  }
  __syncthreads();

  const int j = tid >> 3, qq = tid & 7;
  const int mj = b * 96 + j;

  float lb = bl[h];
#pragma unroll
  for (int d = 0; d < 6; ++d) lb += L[b * 6 + d] * Wl[d * 8 + h];
  const float c_l = 0.5f * lb;
  const float sp = logf(1.0f + __expf(hwts[h]));
  const float c_pt = 0.5f * sp * (1.0f / 12.0f);

  const float4* q4 = reinterpret_cast<const float4*>(praw + (size_t)mj * NCAT_ + h * 16);
  const float4 qa = q4[0], qb = q4[1], qc = q4[2], qd = q4[3];
  float qp[24];
  {
    const float4* qp4 = reinterpret_cast<const float4*>(qpts + ((size_t)mj * 8 + h) * 24);
#pragma unroll
    for (int c4 = 0; c4 < 6; ++c4) {
      const float4 v_ = qp4[c4];
      qp[c4 * 4 + 0] = v_.x; qp[c4 * 4 + 1] = v_.y; qp[c4 * 4 + 2] = v_.z; qp[c4 * 4 + 3] = v_.w;
    }
  }

  float lg[12];
  float mx = -3.0e38f;
#pragma unroll
  for (int s = 0; s < 12; ++s) {
    const int i = s * 8 + qq;
    const float4 ka = k4[i * 5 + 0], kb = k4[i * 5 + 1], kc = k4[i * 5 + 2], kd = k4[i * 5 + 3];
    float dot = qa.x * ka.x + qa.y * ka.y + qa.z * ka.z + qa.w * ka.w
              + qb.x * kb.x + qb.y * kb.y + qb.z * kb.z + qb.w * kb.w
              + qc.x * kc.x + qc.y * kc.y + qc.z * kc.z + qc.w * kc.w
              + qd.x * kd.x + qd.y * kd.y + qd.z * kd.z + qd.w * kd.w;
    float pd = 0.f;
#pragma unroll
    for (int c4 = 0; c4 < 6; ++c4) {
      const float4 kp = kp4[i * 6 + c4];
      const float d0 = qp[c4 * 4 + 0] - kp.x;
      const float d1 = qp[c4 * 4 + 1] - kp.y;
      const float d2 = qp[c4 * 4 + 2] - kp.z;
      const float d3 = qp[c4 * 4 + 3] - kp.w;
      pd += d0 * d0 + d1 * d1 + d2 * d2 + d3 * d3;
    }
    const float lv = dot * 0.125f + 0.5f * lds_b[j * 100 + i] + c_l - c_pt * pd;
    lg[s] = lv;
    mx = fmaxf(mx, lv);
  }
  mx = fmaxf(mx, __shfl_xor(mx, 1));
  mx = fmaxf(mx, __shfl_xor(mx, 2));
  mx = fmaxf(mx, __shfl_xor(mx, 4));
  float sum = 0.f;
#pragma unroll
  for (int s = 0; s < 12; ++s) { lg[s] = __expf(lg[s] - mx); sum += lg[s]; }
  sum += __shfl_xor(sum, 1);
  sum += __shfl_xor(sum, 2);
  sum += __shfl_xor(sum, 4);
  const float inv = 1.0f / sum;

  float acco[16] = {};
  float accp[36] = {};
#pragma unroll
  for (int s = 0; s < 12; ++s) {
    const int i = s * 8 + qq;
    const float w = lg[s];
#pragma unroll
    for (int c4 = 0; c4 < 4; ++c4) {
      const float4 vv = v4[i * 5 + c4];
      acco[c4 * 4 + 0] += w * vv.x; acco[c4 * 4 + 1] += w * vv.y;
      acco[c4 * 4 + 2] += w * vv.z; acco[c4 * 4 + 3] += w * vv.w;
    }
#pragma unroll
    for (int c4 = 0; c4 < 9; ++c4) {
      const float4 pv = vp4[i * 9 + c4];
      accp[c4 * 4 + 0] += w * pv.x; accp[c4 * 4 + 1] += w * pv.y;
      accp[c4 * 4 + 2] += w * pv.z; accp[c4 * 4 + 3] += w * pv.w;
    }
  }
#pragma unroll
  for (int u = 0; u < 16; ++u) {
    acco[u] += __shfl_xor(acco[u], 1); acco[u] += __shfl_xor(acco[u], 2); acco[u] += __shfl_xor(acco[u], 4);
  }
#pragma unroll
  for (int u = 0; u < 36; ++u) {
    accp[u] += __shfl_xor(accp[u], 1); accp[u] += __shfl_xor(accp[u], 2); accp[u] += __shfl_xor(accp[u], 4);
  }

  if (qq == 0) {
    float* orow = ofeat + (size_t)mj * 422;
#pragma unroll
    for (int c = 0; c < 16; ++c) orow[h * 16 + c] = acco[c] * inv;
#pragma unroll
    for (int d = 0; d < 3; ++d)
#pragma unroll
      for (int p = 0; p < 12; ++p)
        orow[128 + d * 96 + h * 12 + p] = accp[p * 3 + d] * inv;
  }
}

// ---------------------------------------------------------------------------
extern "C" void kernel_launch(void* const* d_in, const int* in_sizes, int n_in,
                              void* d_out, int out_size, void* d_ws, size_t ws_size,
                              hipStream_t stream) {
  const float* s     = (const float*)d_in[0];
  const float* z     = (const float*)d_in[1];
  const float* rot   = (const float*)d_in[2];
  const float* trans = (const float*)d_in[3];
  const float* L     = (const float*)d_in[4];
  const float* Wq    = (const float*)d_in[5];
  const float* bq    = (const float*)d_in[6];
  const float* Wkv   = (const float*)d_in[7];
  const float* bkv   = (const float*)d_in[8];
  const float* Wqp   = (const float*)d_in[9];
  const float* bqp   = (const float*)d_in[10];
  const float* Wkvp  = (const float*)d_in[11];
  const float* bkvp  = (const float*)d_in[12];
  const float* Wb    = (const float*)d_in[13];
  const float* bb    = (const float*)d_in[14];
  const float* Wl    = (const float*)d_in[15];
  const float* bl    = (const float*)d_in[16];
  const float* hwts  = (const float*)d_in[17];
  const float* Wout  = (const float*)d_in[18];
  const float* bout  = (const float*)d_in[19];
  float* out = (float*)d_out;
  float* ws  = (float*)d_ws;

  // workspace layout (floats)
  float* praw  = ws;                    // [M,1056]  3244032
  float* qpts  = praw  + 3244032;       // [M,8,8,3]  589824
  float* kpts  = qpts  + 589824;        //            589824
  float* vpts  = kpts  + 589824;        // [M,8,12,3] 884736
  float* ofeat = vpts  + 884736;        // [M,422]   1296384
  float* bT2   = ofeat + 1296384;       // [8,B,96,96] 2359296
  float* Wcat  = bT2   + 2359296;       // [256,1056] 270336
  float* bcat  = Wcat  + 270336;        // [1056]

  pack_w<<<(256 * NCAT_ + 255) / 256, 256, 0, stream>>>(Wq, Wkv, Wqp, Wkvp, bq, bkv, bqp, bkvp, Wcat, bcat);
  gemm64<true ><<<dim3(17, 48), 256, 0, stream>>>(s, Wcat, bcat, praw, NCAT_, 256);
  rotate_pts<<<M_, 256, 0, stream>>>(praw, rot, trans, L, qpts, kpts, vpts, ofeat);
  bpair_kernel<<<2048, 256, 0, stream>>>(z, Wb, bb, bT2);
  attn_kernel<<<256, 768, 0, stream>>>(praw, qpts, kpts, vpts, bT2, L, Wl, bl, hwts, ofeat);
  gemm64<false><<<dim3(4, 48), 256, 0, stream>>>(ofeat, Wout, bout, out, 256, 422);
}